// Round 4
// baseline (1070.692 us; speedup 1.0000x reference)
//
#include <hip/hip_runtime.h>

// ScaledDotProductAttention: B=2,H=16,L=2048,D=128, fp32 in, outputs (x, attn_weight) fp32.
// R6 = R5 hardened. R5's container death is attributed to writing 33.5 MB into d_ws without
// checking ws_size (OOB global writes -> device fault). R6 guards: if ws_size is sufficient,
// run {prep: K/V -> bf16 (V transposed per 64-key tile)} + {attn: pass1 LDS/barrier-free
// K-streaming from L2, pass2 async-split bf16 staging}. Otherwise fall back to the
// known-passing R4 kernel (fp32 staging, 405 us/dispatch). Numerics identical in both paths.

typedef __attribute__((ext_vector_type(8))) __bf16 bf16x8;
typedef __attribute__((ext_vector_type(4))) float f32x4;

#define L_SEQ 2048
#define D_H   128
#define R_Q   128     // q rows per block
#define C_K   64      // keys per k-tile
#define NTHR  512     // 8 waves
#define KPITCH 136    // shorts; 272 B row stride (68 dwords -> 2-way-max b128 reads)
#define VPITCH 72     // shorts; 144 B row stride
#define NKT   (L_SEQ / C_K)
#define NBH   32

__device__ __forceinline__ unsigned short f2bf(float f) {
    unsigned int u = __float_as_uint(f);
    unsigned int r = (u + 0x7FFFu + ((u >> 16) & 1u)) >> 16;  // RNE
    return (unsigned short)r;
}

__device__ __forceinline__ float fexp2(float x) {
#if __has_builtin(__builtin_amdgcn_exp2f)
    return __builtin_amdgcn_exp2f(x);
#else
    return exp2f(x);
#endif
}

__device__ __forceinline__ float rsum16(float v) {
#pragma unroll
    for (int o = 1; o < 16; o <<= 1) v += __shfl_xor(v, o, 64);
    return v;
}

// Raw workgroup barrier with LDS visibility but WITHOUT vmcnt drain.
__device__ __forceinline__ void block_sync() {
    __builtin_amdgcn_sched_barrier(0);
    asm volatile("s_waitcnt lgkmcnt(0)");
    __builtin_amdgcn_s_barrier();
    __builtin_amdgcn_sched_barrier(0);
}

union BF8 {
    bf16x8 v;
    unsigned short s[8];
    uint4 u;
};

// ---------------- prep: K -> bf16 tile-flat [64key][128d]; V -> bf16 tile-flat [128d][64key]
__global__ __launch_bounds__(256) void prep_kernel(
    const float* __restrict__ K, const float* __restrict__ V,
    unsigned short* __restrict__ Kbf, unsigned short* __restrict__ Vbf)
{
    __shared__ float Vld[C_K][D_H + 4];   // 64 x 132 x 4B = 33.8 KB
    const int blk = blockIdx.x;           // 1024 blocks = 32 bh x 32 kt
    const int bh  = blk >> 5, kt = blk & 31;
    const int tid = threadIdx.x;

    const float* Kt = K + ((size_t)bh * L_SEQ + (size_t)kt * C_K) * D_H;
    const float* Vt = V + ((size_t)bh * L_SEQ + (size_t)kt * C_K) * D_H;
    unsigned short* Ko = Kbf + ((size_t)bh * NKT + kt) * (C_K * D_H);
    unsigned short* Vo = Vbf + ((size_t)bh * NKT + kt) * (C_K * D_H);

    // K: 1024 8-elem chunks, flat both sides (coalesced)
#pragma unroll
    for (int i = 0; i < 4; ++i) {
        int c = tid + i * 256;
        const float4* s = reinterpret_cast<const float4*>(Kt) + c * 2;
        float4 a = s[0], b = s[1];
        BF8 t;
        t.s[0] = f2bf(a.x); t.s[1] = f2bf(a.y); t.s[2] = f2bf(a.z); t.s[3] = f2bf(a.w);
        t.s[4] = f2bf(b.x); t.s[5] = f2bf(b.y); t.s[6] = f2bf(b.z); t.s[7] = f2bf(b.w);
        *reinterpret_cast<uint4*>(&Ko[c * 8]) = t.u;
    }
    // V: stage fp32 tile in LDS (coalesced read), then write transposed bf16 (coalesced write)
#pragma unroll
    for (int i = 0; i < 8; ++i) {
        int fc = tid + i * 256;           // float4 id, 2048 total
        int row = fc >> 5, c4 = fc & 31;
        *reinterpret_cast<float4*>(&Vld[row][c4 * 4]) = reinterpret_cast<const float4*>(Vt)[fc];
    }
    __syncthreads();
#pragma unroll
    for (int i = 0; i < 4; ++i) {
        int ch = tid + i * 256;           // 8-key chunk, 1024 total
        int d = ch >> 3, key0 = (ch & 7) * 8;
        BF8 t;
#pragma unroll
        for (int j = 0; j < 8; ++j) t.s[j] = f2bf(Vld[key0 + j][d]);
        *reinterpret_cast<uint4*>(&Vo[ch * 8]) = t.u;   // Vo[d*64 + key] = V[key][d]
    }
}

// ---------------- main attention kernel (bf16-precvt path)
__global__ __launch_bounds__(NTHR, 4) void attn_kernel(
    const float* __restrict__ Q, const unsigned short* __restrict__ Kbf,
    const unsigned short* __restrict__ Vbf, const float* __restrict__ mask,
    const int* __restrict__ pad, float* __restrict__ Xout,
    float* __restrict__ Pout)
{
    __shared__ unsigned short Ks[C_K * KPITCH];   // 17408 B (pass 2 only)
    __shared__ unsigned short Vt[D_H * VPITCH];   // 18432 B (V transposed: [d][key])
    __shared__ unsigned short Ps[R_Q * VPITCH];   // 18432 B (wave-local C/D->A hop)
    __shared__ float PadB[L_SEQ];                 //  8192 B (0 or -inf)
    // total 62464 B -> 2 blocks/CU

    const int tid  = threadIdx.x;
    const int wave = tid >> 6;
    const int lane = tid & 63;
    const int quad = lane >> 4;
    const int l16  = lane & 15;

    const int bh = blockIdx.x & 31;   // same bh -> same XCD group for K/V L2 locality
    const int qt = blockIdx.x >> 5;
    const int b  = bh >> 4;

    const float LOG2E  = 1.44269504088896340736f;
    const float SCALE2 = 0.08838834764831845f * 1.44269504088896340736f;  // (1/sqrt(128))*log2e

    const unsigned short* Kbh = Kbf + (size_t)bh * NKT * (C_K * D_H);
    const unsigned short* Vbh = Vbf + (size_t)bh * NKT * (C_K * D_H);

    // ---- Q fragments straight to registers (A-layout: row=wave*16+l16, k=kb*32+quad*8+j) ----
    BF8 qf[4];
    {
        const float4* qrow = reinterpret_cast<const float4*>(
            Q + ((size_t)bh * L_SEQ + qt * R_Q + wave * 16 + l16) * D_H);
#pragma unroll
        for (int kb = 0; kb < 4; ++kb) {
            float4 a = qrow[kb * 8 + quad * 2];
            float4 c = qrow[kb * 8 + quad * 2 + 1];
            qf[kb].s[0] = f2bf(a.x); qf[kb].s[1] = f2bf(a.y);
            qf[kb].s[2] = f2bf(a.z); qf[kb].s[3] = f2bf(a.w);
            qf[kb].s[4] = f2bf(c.x); qf[kb].s[5] = f2bf(c.y);
            qf[kb].s[6] = f2bf(c.z); qf[kb].s[7] = f2bf(c.w);
        }
    }
    // ---- padding bias (0 / -inf) ----
#pragma unroll
    for (int i = 0; i < 4; ++i) {
        int idx = tid + i * NTHR;
        PadB[idx] = pad[b * L_SEQ + idx] ? -INFINITY : 0.0f;
    }
    __syncthreads();   // PadB visible (prologue; vmcnt drain harmless here)

    // lane owns rows (quad*4 + r), r=0..3 (replicated over the 16 lanes of its quad)
    const long long qrow0 = (long long)(qt * R_Q + wave * 16 + quad * 4);
    const float* maskBase = mask + qrow0 * L_SEQ;

    // =================== PASS 1: row sums, LDS-free & barrier-free ===================
    float lpart[4] = {0.f, 0.f, 0.f, 0.f};
    {
        BF8 fr[2][4];
        auto issueFrag = [&](int slot, int kt, int kb) {
            const unsigned short* Ktile = Kbh + (size_t)kt * (C_K * D_H);
#pragma unroll
            for (int ct = 0; ct < 4; ++ct)
                fr[slot][ct].u = *reinterpret_cast<const uint4*>(
                    &Ktile[(ct * 16 + l16) * D_H + kb * 32 + quad * 8]);
        };
        issueFrag(0, 0, 0);
        issueFrag(1, 0, 1);
        for (int kt = 0; kt < NKT; ++kt) {
            float mk[4][4], pb[4];
#pragma unroll
            for (int ct = 0; ct < 4; ++ct) {
                int kc = kt * C_K + ct * 16 + l16;
                pb[ct] = PadB[kc];
#pragma unroll
                for (int r = 0; r < 4; ++r) mk[ct][r] = maskBase[(long long)r * L_SEQ + kc];
            }
            f32x4 sacc[4];
            f32x4 z4 = {0.f, 0.f, 0.f, 0.f};
#pragma unroll
            for (int ct = 0; ct < 4; ++ct) sacc[ct] = z4;
#pragma unroll
            for (int kb = 0; kb < 4; ++kb) {
                const int slot = kb & 1;
#pragma unroll
                for (int ct = 0; ct < 4; ++ct)
                    sacc[ct] = __builtin_amdgcn_mfma_f32_16x16x32_bf16(
                        qf[kb].v, fr[slot][ct].v, sacc[ct], 0, 0, 0);
                // refill this slot with the group 2 ahead (crosses tile boundary)
                int nkb = kb + 2, nkt = kt;
                if (nkb >= 4) { nkb -= 4; ++nkt; }
                if (nkt < NKT) issueFrag(slot, nkt, nkb);
            }
#pragma unroll
            for (int ct = 0; ct < 4; ++ct)
#pragma unroll
                for (int r = 0; r < 4; ++r) {
                    float m2 = fmaf(mk[ct][r], LOG2E, pb[ct]);          // -inf if padded
                    float e2 = fmaf(sacc[ct][r], SCALE2, m2);
                    lpart[r] += fexp2(e2);                              // exp2(-inf)=0
                }
        }
    }

    float rinv[4];
#pragma unroll
    for (int r = 0; r < 4; ++r) {
        float l = rsum16(lpart[r]);
        rinv[r] = (l > 0.f) ? (1.0f / l) : 0.f;
    }

    // =================== PASS 2: write P, accumulate O = P @ V ===================
    f32x4 oacc[8];
    {
        f32x4 z4 = {0.f, 0.f, 0.f, 0.f};
#pragma unroll
        for (int ct = 0; ct < 8; ++ct) oacc[ct] = z4;
    }
    float* PoutBase = Pout + ((size_t)bh * L_SEQ + (qt * R_Q + wave * 16 + quad * 4)) * L_SEQ;

    uint4 kpre2[2], vpre2[2];
    auto issueK2 = [&](int kt) {
        const uint4* Kt4 = reinterpret_cast<const uint4*>(Kbh + (size_t)kt * (C_K * D_H));
        kpre2[0] = Kt4[tid];
        kpre2[1] = Kt4[tid + NTHR];
    };
    auto writeK2 = [&]() {
#pragma unroll
        for (int i = 0; i < 2; ++i) {
            int c = tid + i * NTHR;           // 8-bf16 chunk: row=c>>4, off=(c&15)*8
            *reinterpret_cast<uint4*>(&Ks[(c >> 4) * KPITCH + (c & 15) * 8]) = kpre2[i];
        }
    };
    auto issueV2 = [&](int kt) {
        const uint4* Vt4 = reinterpret_cast<const uint4*>(Vbh + (size_t)kt * (C_K * D_H));
        vpre2[0] = Vt4[tid];
        vpre2[1] = Vt4[tid + NTHR];
    };
    auto writeV2 = [&]() {
#pragma unroll
        for (int i = 0; i < 2; ++i) {
            int ch = tid + i * NTHR;          // 8-key chunk: d=ch>>3, key0=(ch&7)*8
            *reinterpret_cast<uint4*>(&Vt[(ch >> 3) * VPITCH + (ch & 7) * 8]) = vpre2[i];
        }
    };

    issueK2(0);
    issueV2(0);
    writeK2();   // waits its own vmcnt via register dep
    writeV2();
    for (int kt = 0; kt < NKT; ++kt) {
        block_sync();                 // (A) tile kt's Ks/Vt writes visible
        if (kt + 1 < NKT) { issueK2(kt + 1); issueV2(kt + 1); }  // in flight under compute
        float mk[4][4], pb[4];
#pragma unroll
        for (int ct = 0; ct < 4; ++ct) {
            int kc = kt * C_K + ct * 16 + l16;
            pb[ct] = PadB[kc];
#pragma unroll
            for (int r = 0; r < 4; ++r) mk[ct][r] = maskBase[(long long)r * L_SEQ + kc];
        }
        f32x4 sacc[4];
        {
            f32x4 z4 = {0.f, 0.f, 0.f, 0.f};
#pragma unroll
            for (int ct = 0; ct < 4; ++ct) sacc[ct] = z4;
#pragma unroll
            for (int kb = 0; kb < 4; ++kb) {
#pragma unroll
                for (int ct = 0; ct < 4; ++ct) {
                    bf16x8 bk = *reinterpret_cast<const bf16x8*>(
                        &Ks[(ct * 16 + l16) * KPITCH + kb * 32 + quad * 8]);
                    sacc[ct] = __builtin_amdgcn_mfma_f32_16x16x32_bf16(
                        qf[kb].v, bk, sacc[ct], 0, 0, 0);
                }
            }
        }
#pragma unroll
        for (int ct = 0; ct < 4; ++ct) {
            int kc = kt * C_K + ct * 16 + l16;
#pragma unroll
            for (int r = 0; r < 4; ++r) {
                float m2 = fmaf(mk[ct][r], LOG2E, pb[ct]);
                float e2 = fmaf(sacc[ct][r], SCALE2, m2);
                float p  = fexp2(e2) * rinv[r];
                __builtin_nontemporal_store(p, &PoutBase[(long long)r * L_SEQ + kc]);
                Ps[(wave * 16 + quad * 4 + r) * VPITCH + ct * 16 + l16] = f2bf(p);
            }
        }
        // NO barrier: Ps rows [wave*16, wave*16+16) are written and read by the same wave;
        // in-wave DS ordering + compiler lgkmcnt handles the RAW.
#pragma unroll
        for (int kd = 0; kd < 2; ++kd) {
            bf16x8 ap = *reinterpret_cast<const bf16x8*>(
                &Ps[(wave * 16 + l16) * VPITCH + kd * 32 + quad * 8]);
#pragma unroll
            for (int ct = 0; ct < 8; ++ct) {
                bf16x8 bv = *reinterpret_cast<const bf16x8*>(
                    &Vt[(ct * 16 + l16) * VPITCH + kd * 32 + quad * 8]);
                oacc[ct] = __builtin_amdgcn_mfma_f32_16x16x32_bf16(ap, bv, oacc[ct], 0, 0, 0);
            }
        }
        block_sync();                 // (B) all waves done reading Ks/Vt tile kt
        if (kt + 1 < NKT) { writeK2(); writeV2(); }
    }

    // epilogue: O rows = quad*4+r, cols = ct*16+l16
    float* Xg = Xout + ((size_t)bh * L_SEQ + qt * R_Q + wave * 16 + quad * 4) * D_H;
#pragma unroll
    for (int ct = 0; ct < 8; ++ct)
#pragma unroll
        for (int r = 0; r < 4; ++r)
            __builtin_nontemporal_store(oacc[ct][r], &Xg[r * D_H + ct * 16 + l16]);
}

// ---------------- fallback kernel (R4, fp32 inputs, known-passing 405 us/dispatch)
__global__ __launch_bounds__(NTHR, 4) void attn_kernel_fb(
    const float* __restrict__ Q, const float* __restrict__ K,
    const float* __restrict__ V, const float* __restrict__ mask,
    const int* __restrict__ pad, float* __restrict__ Xout,
    float* __restrict__ Pout)
{
    __shared__ unsigned short Ks[C_K * KPITCH];
    __shared__ unsigned short Vt[D_H * VPITCH];
    __shared__ unsigned short Ps[R_Q * VPITCH];
    __shared__ float PadB[L_SEQ];

    const int tid  = threadIdx.x;
    const int wave = tid >> 6;
    const int lane = tid & 63;
    const int quad = lane >> 4;
    const int l16  = lane & 15;

    const int bh = blockIdx.x & 31;
    const int qt = blockIdx.x >> 5;
    const int b  = bh >> 4;

    const float LOG2E  = 1.44269504088896340736f;
    const float SCALE2 = 0.08838834764831845f * 1.44269504088896340736f;

    const float* Kg0 = K + (long long)bh * L_SEQ * D_H;
    const float* Vg0 = V + (long long)bh * L_SEQ * D_H;

    BF8 qf[4];
    {
        const float4* qrow = reinterpret_cast<const float4*>(
            Q + ((long long)bh * L_SEQ + qt * R_Q + wave * 16 + l16) * D_H);
#pragma unroll
        for (int kb = 0; kb < 4; ++kb) {
            float4 a = qrow[kb * 8 + quad * 2];
            float4 c = qrow[kb * 8 + quad * 2 + 1];
            qf[kb].s[0] = f2bf(a.x); qf[kb].s[1] = f2bf(a.y);
            qf[kb].s[2] = f2bf(a.z); qf[kb].s[3] = f2bf(a.w);
            qf[kb].s[4] = f2bf(c.x); qf[kb].s[5] = f2bf(c.y);
            qf[kb].s[6] = f2bf(c.z); qf[kb].s[7] = f2bf(c.w);
        }
    }
#pragma unroll
    for (int i = 0; i < 4; ++i) {
        int idx = tid + i * NTHR;
        PadB[idx] = pad[b * L_SEQ + idx] ? -INFINITY : 0.0f;
    }

    float4 kpre[4];
    float  vpre[16];

    auto issueK = [&](int kt) {
        const float4* Kg = reinterpret_cast<const float4*>(Kg0 + (long long)kt * C_K * D_H);
#pragma unroll
        for (int i = 0; i < 2; ++i) {
            int c = tid + i * NTHR;
            kpre[2 * i]     = Kg[c * 2];
            kpre[2 * i + 1] = Kg[c * 2 + 1];
        }
    };
    auto writeK = [&]() {
#pragma unroll
        for (int i = 0; i < 2; ++i) {
            int c = tid + i * NTHR;
            int row = c >> 4, off = (c & 15) * 8;
            float4 a = kpre[2 * i];
            float4 d = kpre[2 * i + 1];
            BF8 t;
            t.s[0] = f2bf(a.x); t.s[1] = f2bf(a.y); t.s[2] = f2bf(a.z); t.s[3] = f2bf(a.w);
            t.s[4] = f2bf(d.x); t.s[5] = f2bf(d.y); t.s[6] = f2bf(d.z); t.s[7] = f2bf(d.w);
            *reinterpret_cast<uint4*>(&Ks[row * KPITCH + off]) = t.u;
        }
    };
    auto issueV = [&](int kt) {
        const float* Vg = Vg0 + (long long)kt * C_K * D_H;
        int c = tid & 127;
#pragma unroll
        for (int i = 0; i < 2; ++i) {
            int key0 = (((tid >> 7) + i * 4) << 3);
#pragma unroll
            for (int j = 0; j < 8; ++j)
                vpre[i * 8 + j] = Vg[(key0 + j) * D_H + c];
        }
    };
    auto writeV = [&]() {
        int c = tid & 127;
#pragma unroll
        for (int i = 0; i < 2; ++i) {
            int key0 = (((tid >> 7) + i * 4) << 3);
            BF8 t;
#pragma unroll
            for (int j = 0; j < 8; ++j) t.s[j] = f2bf(vpre[i * 8 + j]);
            *reinterpret_cast<uint4*>(&Vt[c * VPITCH + key0]) = t.u;
        }
    };

    auto computeS = [&](f32x4* sacc) {
        f32x4 z4 = {0.f, 0.f, 0.f, 0.f};
#pragma unroll
        for (int ct = 0; ct < 4; ++ct) sacc[ct] = z4;
#pragma unroll
        for (int kb = 0; kb < 4; ++kb) {
#pragma unroll
            for (int ct = 0; ct < 4; ++ct) {
                bf16x8 bk = *reinterpret_cast<const bf16x8*>(
                    &Ks[(ct * 16 + l16) * KPITCH + kb * 32 + quad * 8]);
                sacc[ct] = __builtin_amdgcn_mfma_f32_16x16x32_bf16(qf[kb].v, bk, sacc[ct], 0, 0, 0);
            }
        }
    };

    const long long qrow0 = (long long)(qt * R_Q + wave * 16 + quad * 4);
    const float* maskBase = mask + qrow0 * L_SEQ;

    float lpart[4] = {0.f, 0.f, 0.f, 0.f};
    issueK(0);
    writeK();
    for (int kt = 0; kt < NKT; ++kt) {
        block_sync();
        if (kt + 1 < NKT) issueK(kt + 1);
        float mk[4][4], pb[4];
#pragma unroll
        for (int ct = 0; ct < 4; ++ct) {
            int kc = kt * C_K + ct * 16 + l16;
            pb[ct] = PadB[kc];
#pragma unroll
            for (int r = 0; r < 4; ++r) mk[ct][r] = maskBase[(long long)r * L_SEQ + kc];
        }
        f32x4 sacc[4];
        computeS(sacc);
#pragma unroll
        for (int ct = 0; ct < 4; ++ct)
#pragma unroll
            for (int r = 0; r < 4; ++r) {
                float m2 = fmaf(mk[ct][r], LOG2E, pb[ct]);
                float e2 = fmaf(sacc[ct][r], SCALE2, m2);
                lpart[r] += fexp2(e2);
            }
        block_sync();
        if (kt + 1 < NKT) writeK();
    }

    float rinv[4];
#pragma unroll
    for (int r = 0; r < 4; ++r) {
        float l = rsum16(lpart[r]);
        rinv[r] = (l > 0.f) ? (1.0f / l) : 0.f;
    }

    f32x4 oacc[8];
    {
        f32x4 z4 = {0.f, 0.f, 0.f, 0.f};
#pragma unroll
        for (int ct = 0; ct < 8; ++ct) oacc[ct] = z4;
    }
    float* PoutBase = Pout + ((long long)bh * L_SEQ + (qt * R_Q + quad * 4 + wave * 16)) * L_SEQ;

    issueK(0);
    issueV(0);
    writeK();
    writeV();
    for (int kt = 0; kt < NKT; ++kt) {
        block_sync();
        if (kt + 1 < NKT) { issueK(kt + 1); issueV(kt + 1); }
        float mk[4][4], pb[4];
#pragma unroll
        for (int ct = 0; ct < 4; ++ct) {
            int kc = kt * C_K + ct * 16 + l16;
            pb[ct] = PadB[kc];
#pragma unroll
            for (int r = 0; r < 4; ++r) mk[ct][r] = maskBase[(long long)r * L_SEQ + kc];
        }
        f32x4 sacc[4];
        computeS(sacc);
#pragma unroll
        for (int ct = 0; ct < 4; ++ct) {
            int kc = kt * C_K + ct * 16 + l16;
#pragma unroll
            for (int r = 0; r < 4; ++r) {
                float m2 = fmaf(mk[ct][r], LOG2E, pb[ct]);
                float e2 = fmaf(sacc[ct][r], SCALE2, m2);
                float p  = fexp2(e2) * rinv[r];
                __builtin_nontemporal_store(p, &PoutBase[(long long)r * L_SEQ + kc]);
                Ps[(wave * 16 + quad * 4 + r) * VPITCH + ct * 16 + l16] = f2bf(p);
            }
        }
#pragma unroll
        for (int kd = 0; kd < 2; ++kd) {
            bf16x8 ap = *reinterpret_cast<const bf16x8*>(
                &Ps[(wave * 16 + l16) * VPITCH + kd * 32 + quad * 8]);
#pragma unroll
            for (int ct = 0; ct < 8; ++ct) {
                bf16x8 bv = *reinterpret_cast<const bf16x8*>(
                    &Vt[(ct * 16 + l16) * VPITCH + kd * 32 + quad * 8]);
                oacc[ct] = __builtin_amdgcn_mfma_f32_16x16x32_bf16(ap, bv, oacc[ct], 0, 0, 0);
            }
        }
        block_sync();
        if (kt + 1 < NKT) { writeK(); writeV(); }
    }

    float* Xg = Xout + ((long long)bh * L_SEQ + qt * R_Q + wave * 16 + quad * 4) * D_H;
#pragma unroll
    for (int ct = 0; ct < 8; ++ct)
#pragma unroll
        for (int r = 0; r < 4; ++r)
            __builtin_nontemporal_store(oacc[ct][r], &Xg[r * D_H + ct * 16 + l16]);
}

extern "C" void kernel_launch(void* const* d_in, const int* in_sizes, int n_in,
                              void* d_out, int out_size, void* d_ws, size_t ws_size,
                              hipStream_t stream) {
    const float* Q    = (const float*)d_in[0];
    const float* K    = (const float*)d_in[1];
    const float* V    = (const float*)d_in[2];
    const float* mask = (const float*)d_in[3];
    const int*   pad  = (const int*)d_in[4];   // bool input -> int32 per harness dtype rules
    float* Xout = (float*)d_out;
    float* Pout = (float*)d_out + (long long)2 * 16 * 2048 * 128;  // x first, then attn weights

    const size_t kv_elems = (size_t)NBH * L_SEQ * D_H;              // 8.39M bf16 each
    const size_t need     = 2 * kv_elems * sizeof(unsigned short);  // 33.55 MB

    if (d_ws != nullptr && ws_size >= need) {
        unsigned short* Kbf = (unsigned short*)d_ws;
        unsigned short* Vbf = Kbf + kv_elems;
        prep_kernel<<<dim3(NBH * NKT), dim3(256), 0, stream>>>(K, V, Kbf, Vbf);
        attn_kernel<<<dim3(512), dim3(NTHR), 0, stream>>>(Q, Kbf, Vbf, mask, pad, Xout, Pout);
    } else {
        attn_kernel_fb<<<dim3(512), dim3(NTHR), 0, stream>>>(Q, K, V, mask, pad, Xout, Pout);
    }
}